// Round 22
// baseline (1234.640 us; speedup 1.0000x reference)
//
#include <hip/hip_runtime.h>
#include <math.h>

#define B_   16
#define N_   2048
#define S_   1025
#define K_   16
#define EMB_ 64
#define NF_  (B_ * S_ * K_)   // 262400
#define NCH_ (NF_ / 64)       // 4100
#define NBS_ (NCH_ * 4)       // 16400
#define NBLK 256
#define PK_UNITS 513
#define KNN_ITEMS (129 * 16)  // 2064

typedef float v2f __attribute__((ext_vector_type(2)));
typedef short bf16x8 __attribute__((ext_vector_type(8)));
typedef float f32x4 __attribute__((ext_vector_type(4)));

#define AL(p)    __hip_atomic_load((p), __ATOMIC_ACQUIRE, __HIP_MEMORY_SCOPE_AGENT)
#define ALR(p)   __hip_atomic_load((p), __ATOMIC_RELAXED, __HIP_MEMORY_SCOPE_AGENT)
#define ASR(p,v) __hip_atomic_store((p), (v), __ATOMIC_RELEASE, __HIP_MEMORY_SCOPE_AGENT)
#define AADD(p)  __hip_atomic_fetch_add((p), 1, __ATOMIC_ACQ_REL, __HIP_MEMORY_SCOPE_AGENT)

__device__ __forceinline__ unsigned short f2bf(float f) {
  unsigned u = __float_as_uint(f);
  u += 0x7fffu + ((u >> 16) & 1u);
  return (unsigned short)(u >> 16);
}
__device__ __forceinline__ float bfl(unsigned pk) { return __uint_as_float((pk & 0xffffu) << 16); }
__device__ __forceinline__ float bfh(unsigned pk) { return __uint_as_float(pk & 0xffff0000u); }

__device__ __forceinline__ float rowsum16(float v) {
#define RADD(CTRL) { int tm_ = __builtin_amdgcn_update_dpp(0, __float_as_int(v), (CTRL), 0xF, 0xF, true); \
                     v += __int_as_float(tm_); }
  RADD(0x111) RADD(0x112) RADD(0x114) RADD(0x118)
#undef RADD
  return v;
}

__global__ void diag_kernel(float* out, float v) {
  if (threadIdx.x == 0 && blockIdx.x == 0) out[0] = v;
}

// ======== phase0: FPS (0-15) || pk/wconv + gated knn (16-255) ========
// BALLAST: 28 pinned live-across-loop registers force the allocator out of the tight
// ~108-VGPR schedule (817us) back to the wide schedule regime (614us at >=132 VGPR).
__global__ __launch_bounds__(256, 1)
void phase0_kernel(const float* __restrict__ xy, const float* __restrict__ fea,
                   const float* __restrict__ W1,
                   const float* __restrict__ W2, const float* __restrict__ W3,
                   int* fps_idx, float* new_xyz, int* knn_sel,
                   unsigned* Pp, unsigned short* W2b, unsigned short* W3b,
                   float* out0, int* flags) {
  __shared__ float2 sh_lxy[N_];     // 16 KB
  __shared__ double sh_lsq[N_];     // 16 KB
  __shared__ float sh_pkA[4096];    // 16 KB
  __shared__ float sh_pkB[4096];    // 16 KB
  __shared__ int sh_unit;
  const int bid = blockIdx.x;
  const int tid = threadIdx.x;
  int* progress = flags + 8;

  if (bid < 16) {
    // ---- FPS: validated body + progress publishing ----
    const int b = bid;
    const int lane = tid;
    const float* xb = xy + (size_t)b * 2 * N_;
    v2f pxp[16], pyp[16];
    float dist[32];
    float ballast[28];
    if (lane < 64) {
      const float2* xb2 = (const float2*)xb;
      const float2* yb2 = (const float2*)(xb + N_);
#pragma unroll
      for (int q = 0; q < 16; ++q) {
        float2 x01 = xb2[lane * 16 + q];
        float2 y01 = yb2[lane * 16 + q];
        int p = lane * 32 + 2 * q;
        sh_lxy[p] = make_float2(x01.x, y01.x);
        sh_lxy[p + 1] = make_float2(x01.y, y01.y);
        pxp[q][0] = x01.x; pxp[q][1] = x01.y;
        pyp[q][0] = y01.x; pyp[q][1] = y01.y;
        dist[2 * q] = __builtin_inff();
        dist[2 * q + 1] = __builtin_inff();
      }
#pragma unroll
      for (int q = 0; q < 16; ++q) {
        asm volatile("" : "+v"(pxp[q]), "+v"(pyp[q]));
      }
      // live-range ballast: opaque registers held across the whole loop
#pragma unroll
      for (int q = 0; q < 28; ++q) {
        ballast[q] = xb[lane + q];
        asm volatile("" : "+v"(ballast[q]));
      }
    }
    __syncthreads();
    if (lane < 64) {
      int cur = 0;
      for (int t = 0; t < S_; ++t) {
        float2 c = sh_lxy[cur];
        if (lane == 0) {
          fps_idx[b * S_ + t] = cur;
          new_xyz[(b * S_ + t) * 2 + 0] = c.x;
          new_xyz[(b * S_ + t) * 2 + 1] = c.y;
          out0[b * 2 * S_ + t] = c.x;
          out0[b * 2 * S_ + S_ + t] = c.y;
        }
        const float ncx = -c.x, ncy = -c.y;
        v2f ncx2; ncx2[0] = ncx; ncx2[1] = ncx;
        v2f ncy2; ncy2[0] = ncy; ncy2[1] = ncy;
#pragma unroll
        for (int q = 0; q < 16; ++q) {
          v2f dx, dy, sx, sy, dd;
          asm("v_pk_add_f32 %0, %1, %2" : "=v"(dx) : "v"(pxp[q]), "v"(ncx2));
          asm("v_pk_add_f32 %0, %1, %2" : "=v"(dy) : "v"(pyp[q]), "v"(ncy2));
          asm("v_pk_mul_f32 %0, %1, %1" : "=v"(sx) : "v"(dx));
          asm("v_pk_mul_f32 %0, %1, %1" : "=v"(sy) : "v"(dy));
          asm("v_pk_add_f32 %0, %1, %2" : "=v"(dd) : "v"(sx), "v"(sy));
          dist[2 * q] = fminf(dist[2 * q], dd[0]);
          dist[2 * q + 1] = fminf(dist[2 * q + 1], dd[1]);
        }
        float m1[16], m2[8], m3[4], m4[2];
#pragma unroll
        for (int j = 0; j < 16; ++j) m1[j] = fmaxf(dist[2 * j], dist[2 * j + 1]);
#pragma unroll
        for (int j = 0; j < 8; ++j) m2[j] = fmaxf(m1[2 * j], m1[2 * j + 1]);
#pragma unroll
        for (int j = 0; j < 4; ++j) m3[j] = fmaxf(m2[2 * j], m2[2 * j + 1]);
        m4[0] = fmaxf(m3[0], m3[1]);
        m4[1] = fmaxf(m3[2], m3[3]);
        const float lmax = fmaxf(m4[0], m4[1]);
        int xr = __float_as_int(lmax);
#define DPP_MAX_STEP(CTRL)                                                        \
        {                                                                         \
          int tmp_ = __builtin_amdgcn_update_dpp(xr, xr, (CTRL), 0xF, 0xF, false);\
          xr = __float_as_int(fmaxf(__int_as_float(xr), __int_as_float(tmp_)));   \
        }
        DPP_MAX_STEP(0x111)
        DPP_MAX_STEP(0x112)
        DPP_MAX_STEP(0x114)
        DPP_MAX_STEP(0x118)
        DPP_MAX_STEP(0x142)
        DPP_MAX_STEP(0x143)
#undef DPP_MAX_STEP
        const float g = __int_as_float(__builtin_amdgcn_readlane(xr, 63));
        int n = (m4[0] == g) ? 0 : 1;
        float c3 = (n & 1) ? m3[2] : m3[0];
        n = 2 * n + ((c3 == g) ? 0 : 1);
        float lo2 = (n & 1) ? m2[2] : m2[0];
        float hi2 = (n & 1) ? m2[6] : m2[4];
        float c2 = (n & 2) ? hi2 : lo2;
        n = 2 * n + ((c2 == g) ? 0 : 1);
        float a0 = (n & 1) ? m1[2] : m1[0];
        float a1v = (n & 1) ? m1[6] : m1[4];
        float a2v = (n & 1) ? m1[10] : m1[8];
        float a3v = (n & 1) ? m1[14] : m1[12];
        float b0 = (n & 2) ? a1v : a0;
        float b1v = (n & 2) ? a3v : a2v;
        float c1 = (n & 4) ? b1v : b0;
        n = 2 * n + ((c1 == g) ? 0 : 1);
        float e0 = (n & 1) ? dist[2] : dist[0];
        float e1 = (n & 1) ? dist[6] : dist[4];
        float e2 = (n & 1) ? dist[10] : dist[8];
        float e3 = (n & 1) ? dist[14] : dist[12];
        float e4 = (n & 1) ? dist[18] : dist[16];
        float e5 = (n & 1) ? dist[22] : dist[20];
        float e6 = (n & 1) ? dist[26] : dist[24];
        float e7 = (n & 1) ? dist[30] : dist[28];
        float f0 = (n & 2) ? e1 : e0;
        float f1 = (n & 2) ? e3 : e2;
        float f2 = (n & 2) ? e5 : e4;
        float f3 = (n & 2) ? e7 : e6;
        float g0 = (n & 4) ? f1 : f0;
        float g1v = (n & 4) ? f3 : f2;
        float c0 = (n & 8) ? g1v : g0;
        const int lf = 2 * n + ((c0 == g) ? 0 : 1);
        unsigned long long mask = __ballot(lmax == g);
        int first = __ffsll(mask) - 1;
        cur = __builtin_amdgcn_readlane(lane * 32 + lf, first);
        if (lane == 0 && ((t & 31) == 31 || t == S_ - 1)) {
          ASR(&progress[b], t + 1);
        }
      }
      // keep ballast live to the end of the loop region
#pragma unroll
      for (int q = 0; q < 28; ++q) {
        asm volatile("" :: "v"(ballast[q]));
      }
    }
  } else {
    // ---- workers: pk / wconv (work-steal) ----
    for (;;) {
      __syncthreads();
      if (tid == 0) sh_unit = AADD(&flags[2]);
      __syncthreads();
      int u = sh_unit;
      if (u >= PK_UNITS) break;
      if (u < 512) {
        const int b = u >> 5;
        const int pt0 = (u & 31) << 6;
#pragma unroll
        for (int p = 0; p < 16; ++p) {
          int idx = tid + 256 * p;
          int c = idx >> 6, e = idx & 63;
          sh_pkA[e * 64 + c] = W1[c * 66 + 2 + e];
          int r = (tid >> 6) + 4 * p, cc = tid & 63;
          sh_pkB[r * 64 + cc] = fea[((size_t)b * 64 + r) * N_ + pt0 + cc];
        }
        __syncthreads();
        const int tpt = tid & 15, tcq = tid >> 4;
        float acc[4][4];
#pragma unroll
        for (int i = 0; i < 4; ++i)
#pragma unroll
          for (int j = 0; j < 4; ++j) acc[i][j] = 0.f;
        for (int e = 0; e < 64; ++e) {
          float4 a4 = *reinterpret_cast<const float4*>(&sh_pkA[e * 64 + tcq * 4]);
          float4 b4 = *reinterpret_cast<const float4*>(&sh_pkB[e * 64 + tpt * 4]);
          const float av[4] = {a4.x, a4.y, a4.z, a4.w};
          const float bvv[4] = {b4.x, b4.y, b4.z, b4.w};
#pragma unroll
          for (int i = 0; i < 4; ++i)
#pragma unroll
            for (int j = 0; j < 4; ++j) acc[i][j] = fmaf(av[i], bvv[j], acc[i][j]);
        }
#pragma unroll
        for (int j = 0; j < 4; ++j) {
          int pt = tpt * 4 + j;
          unsigned lo = (unsigned)f2bf(acc[0][j]) | ((unsigned)f2bf(acc[1][j]) << 16);
          unsigned hi = (unsigned)f2bf(acc[2][j]) | ((unsigned)f2bf(acc[3][j]) << 16);
          unsigned* dst = &Pp[((size_t)(b * N_ + pt0 + pt)) * 32 + tcq * 2];
          dst[0] = lo;
          dst[1] = hi;
        }
      } else {
        for (int i = tid; i < 128 * 64; i += 256) W2b[i] = f2bf(W2[i]);
        for (int i = tid; i < 256 * 128; i += 256) W3b[i] = f2bf(W3[i]);
      }
    }
    // ---- workers: knn items (work-steal, gated on FPS progress) ----
    for (;;) {
      __syncthreads();
      if (tid == 0) sh_unit = AADD(&flags[4]);
      __syncthreads();
      int it = sh_unit;
      if (it >= KNN_ITEMS) break;
      const int b = it & 15;
      const int s0 = (it >> 4) * 8;
      const int sHi = (s0 + 8 < S_) ? (s0 + 8) : S_;
      if (tid == 0) {
        while (AL(&progress[b]) < sHi) __builtin_amdgcn_s_sleep(8);
      }
      __syncthreads();
      const float* xb = xy + (size_t)b * 2 * N_;
      for (int p = tid; p < N_; p += 256) {
        float x = xb[p], y = xb[N_ + p];
        sh_lxy[p] = make_float2(x, y);
        sh_lsq[p] = (double)x * (double)x + (double)y * (double)y;
      }
      __syncthreads();
      const int s = s0 + (tid >> 5);
      const int oct = tid & 31;
      if (s < S_) {
        const int p0 = ALR((int*)&fps_idx[b * S_ + s]);
        float2 q = sh_lxy[p0];
        const double xn = (double)q.x, yn = (double)q.y;
        const double sqn = sh_lsq[p0];
        double d16[16];
        int i16[16];
#pragma unroll
        for (int j = 0; j < 16; ++j) { d16[j] = __builtin_inf(); i16[j] = 0x7fffffff; }
        const int mlo = oct * 64;
        for (int m0 = mlo; m0 < mlo + 64; m0 += 4) {
          double dd[4];
#pragma unroll
          for (int u2 = 0; u2 < 4; ++u2) {
            float2 p = sh_lxy[m0 + u2];
            double dot = (double)p.x * xn + (double)p.y * yn;
            dd[u2] = (sqn - 2.0 * dot) + sh_lsq[m0 + u2];
          }
#pragma unroll
          for (int u2 = 0; u2 < 4; ++u2) {
            if (dd[u2] < d16[15]) {
              double d = dd[u2];
              int mi = m0 + u2;
#pragma unroll
              for (int j = 15; j >= 1; --j) {
                bool shift = d < d16[j - 1];
                bool ins = d < d16[j];
                d16[j] = shift ? d16[j - 1] : (ins ? d : d16[j]);
                i16[j] = shift ? i16[j - 1] : (ins ? mi : i16[j]);
              }
              if (d < d16[0]) { d16[0] = d; i16[0] = mi; }
            }
          }
        }
#pragma unroll
        for (int w = 1; w <= 16; w <<= 1) {
          double nd[16]; int ni[16];
#pragma unroll
          for (int i = 0; i < 16; ++i) {
            double rd = __shfl_xor(d16[15 - i], w, 64);
            int ri = __shfl_xor(i16[15 - i], w, 64);
            bool takeR = (rd < d16[i]) || (rd == d16[i] && ri < i16[i]);
            nd[i] = takeR ? rd : d16[i];
            ni[i] = takeR ? ri : i16[i];
          }
#pragma unroll
          for (int i = 0; i < 16; ++i) { d16[i] = nd[i]; i16[i] = ni[i]; }
          if (w < 16) {
#pragma unroll
            for (int dstg = 8; dstg >= 1; dstg >>= 1) {
#pragma unroll
              for (int i = 0; i < 16; ++i) {
                if ((i & dstg) == 0) {
                  int a = i, c = i + dstg;
                  bool sw = (d16[a] > d16[c]) || (d16[a] == d16[c] && i16[a] > i16[c]);
                  double tlo = sw ? d16[c] : d16[a];
                  double thi = sw ? d16[a] : d16[c];
                  int ulo = sw ? i16[c] : i16[a];
                  int uhi = sw ? i16[a] : i16[c];
                  d16[a] = tlo; d16[c] = thi; i16[a] = ulo; i16[c] = uhi;
                }
              }
            }
          }
        }
        if (oct == 0) {
          int* dst = knn_sel + ((size_t)b * S_ + s) * K_;
#pragma unroll
          for (int j = 0; j < 16; ++j) dst[j] = i16[j];
        }
      }
    }
  }
}

// ---------------- yk1 (r18 validated) ----------------
__global__ __launch_bounds__(256) void yk1_kernel(const float* __restrict__ xy,
                                                  const int* __restrict__ knn_sel,
                                                  const float* __restrict__ new_xyz,
                                                  const unsigned* __restrict__ Pp,
                                                  const float* __restrict__ W1,
                                                  const float* __restrict__ b1,
                                                  unsigned* __restrict__ Y1p) {
  __shared__ float w0s[64], w1s[64], bbs[64];
  const int t = threadIdx.x;
  if (t < 64) { w0s[t] = W1[t * 66 + 0]; w1s[t] = W1[t * 66 + 1]; bbs[t] = b1[t]; }
  __syncthreads();
  const int n = blockIdx.x * 256 + t;
  const int bs = n >> 4;
  const int b = bs / S_;
  const int nbr = knn_sel[n];
  const float dx = xy[(size_t)b * 2 * N_ + nbr] - new_xyz[bs * 2 + 0];
  const float dy = xy[(size_t)b * 2 * N_ + N_ + nbr] - new_xyz[bs * 2 + 1];
  const unsigned* prow = &Pp[((size_t)(b * N_ + nbr)) * 32];
#pragma unroll 8
  for (int j = 0; j < 32; ++j) {
    unsigned pj = prow[j];
    int c = 2 * j;
    float v0 = bfl(pj) + w0s[c] * dx + w1s[c] * dy + bbs[c];
    float v1 = bfh(pj) + w0s[c + 1] * dx + w1s[c + 1] * dy + bbs[c + 1];
    Y1p[(size_t)j * NF_ + n] = (unsigned)f2bf(v0) | ((unsigned)f2bf(v1) << 16);
  }
}

// ---------------- rowstats (r18 validated) ----------------
__global__ __launch_bounds__(256) void rowstats_kernel(const unsigned* __restrict__ Y1p,
                                                       float* __restrict__ parts) {
  const int j = blockIdx.x & 31;
  const int seg = blockIdx.x >> 5;
  const int SEG = NF_ / 8;
  const unsigned* p = Y1p + (size_t)j * NF_ + (size_t)seg * SEG;
  double s0 = 0, q0 = 0, s1 = 0, q1 = 0;
  for (int i = threadIdx.x; i < SEG; i += 256) {
    unsigned pk = p[i];
    double a = (double)bfl(pk), b = (double)bfh(pk);
    s0 += a; q0 = fma(a, a, q0);
    s1 += b; q1 = fma(b, b, q1);
  }
  __shared__ double sh[4][256];
  sh[0][threadIdx.x] = s0; sh[1][threadIdx.x] = q0;
  sh[2][threadIdx.x] = s1; sh[3][threadIdx.x] = q1;
  __syncthreads();
  for (int o = 128; o > 0; o >>= 1) {
    if (threadIdx.x < o) {
#pragma unroll
      for (int u = 0; u < 4; ++u) sh[u][threadIdx.x] += sh[u][threadIdx.x + o];
    }
    __syncthreads();
  }
  if (threadIdx.x == 0) {
    float* dst = parts + (size_t)(j * 8 + seg) * 4;
    dst[0] = (float)sh[0][0];
    dst[1] = (float)sh[2][0];
    dst[2] = (float)sh[1][0];
    dst[3] = (float)sh[3][0];
  }
}

// ---------------- redabsch1 (r18 validated) ----------------
__global__ void redabsch1_kernel(const float* __restrict__ parts,
                                 const float* __restrict__ g, const float* __restrict__ be,
                                 float* __restrict__ A, float* __restrict__ D) {
  int m = threadIdx.x;
  if (m >= 64) return;
  int j = m >> 1, par = m & 1;
  double a = 0.0, b = 0.0;
  for (int seg = 0; seg < 8; ++seg) {
    const float* src = parts + (size_t)(j * 8 + seg) * 4;
    a += (double)src[par];
    b += (double)src[2 + par];
  }
  double mu = a * (1.0 / NF_);
  double var = b * (1.0 / NF_) - mu * mu;
  double aa = (double)g[m] / sqrt(var + 1e-5);
  A[m] = (float)aa;
  D[m] = (float)((double)be[m] - aa * mu);
}

// ---------------- redabsch (r18 validated) ----------------
__global__ void redabsch_kernel(const float* __restrict__ parts, int P, int M,
                                const float* __restrict__ g, const float* __restrict__ be,
                                float* __restrict__ A, float* __restrict__ D) {
  int m = threadIdx.x;
  if (m >= M) return;
  double a = 0.0, b = 0.0;
  for (int p = 0; p < P; ++p) {
    a += (double)parts[(size_t)p * 2 * M + m];
    b += (double)parts[(size_t)p * 2 * M + M + m];
  }
  double mu = a * (1.0 / NF_);
  double var = b * (1.0 / NF_) - mu * mu;
  double aa = (double)g[m] / sqrt(var + 1e-5);
  A[m] = (float)aa;
  D[m] = (float)((double)be[m] - aa * mu);
}

__device__ __forceinline__ void stage_x1(const unsigned* Y1p, const float* ab1, char* x1c,
                                         size_t n0, int w, int L) {
#pragma unroll
  for (int e = 0; e < 8; ++e) {
    int k0 = 2 * (w + 4 * e);
    unsigned pkv = Y1p[(size_t)(k0 >> 1) * NF_ + n0 + L];
    float v0 = fmaxf(fmaf(bfl(pkv), ab1[k0], ab1[64 + k0]), 0.f);
    float v1 = fmaxf(fmaf(bfh(pkv), ab1[k0 + 1], ab1[64 + k0 + 1]), 0.f);
    unsigned pk = (unsigned)f2bf(v0) | ((unsigned)f2bf(v1) << 16);
    *reinterpret_cast<unsigned*>(&x1c[L * 128 + ((2 * k0) ^ ((L & 7) << 4))]) = pk;
  }
}

// ============ passA (r18 validated) ============
__global__ __launch_bounds__(256) void passA_mfma_kernel(
    const unsigned* __restrict__ Y1p, const unsigned short* __restrict__ W2b,
    const float* __restrict__ A1v, const float* __restrict__ Bc1v,
    float* __restrict__ parts) {
  __shared__ float ab1[128];
  __shared__ __align__(16) unsigned short x1b[64 * 64];
  const int t = threadIdx.x;
  const int w = t >> 6, L = t & 63;
  if (t < 128) ab1[t] = (t < 64) ? A1v[t] : Bc1v[t - 64];
  bf16x8 w2f[2][2];
#pragma unroll
  for (int rb = 0; rb < 2; ++rb)
#pragma unroll
    for (int ks = 0; ks < 2; ++ks) {
      int row = (2 * w + rb) * 16 + (L & 15);
      int koff = ks * 32 + (L >> 4) * 8;
      w2f[rb][ks] = *reinterpret_cast<const bf16x8*>(&W2b[row * 64 + koff]);
    }
  float vs[2][4], vq[2][4];
#pragma unroll
  for (int rb = 0; rb < 2; ++rb)
#pragma unroll
    for (int r = 0; r < 4; ++r) { vs[rb][r] = 0.f; vq[rb][r] = 0.f; }
  char* x1c = reinterpret_cast<char*>(x1b);
  for (int ch = blockIdx.x; ch < NCH_; ch += 512) {
    const size_t n0 = (size_t)ch * 64;
    __syncthreads();
    stage_x1(Y1p, ab1, x1c, n0, w, L);
    __syncthreads();
#pragma unroll
    for (int rb = 0; rb < 2; ++rb) {
      f32x4 acc2[4];
#pragma unroll
      for (int cb = 0; cb < 4; ++cb) acc2[cb][0] = acc2[cb][1] = acc2[cb][2] = acc2[cb][3] = 0.f;
#pragma unroll
      for (int ks = 0; ks < 2; ++ks)
#pragma unroll
        for (int cb = 0; cb < 4; ++cb) {
          int n = cb * 16 + (L & 15);
          int koff = ks * 32 + (L >> 4) * 8;
          bf16x8 bfr = *reinterpret_cast<const bf16x8*>(&x1c[n * 128 + ((2 * koff) ^ ((n & 7) << 4))]);
          acc2[cb] = __builtin_amdgcn_mfma_f32_16x16x32_bf16(w2f[rb][ks], bfr, acc2[cb], 0, 0, 0);
        }
#pragma unroll
      for (int cb = 0; cb < 4; ++cb)
#pragma unroll
        for (int r = 0; r < 4; ++r) {
          float y = acc2[cb][r];
          vs[rb][r] += y;
          vq[rb][r] = fmaf(y, y, vq[rb][r]);
        }
    }
  }
#pragma unroll
  for (int rb = 0; rb < 2; ++rb)
#pragma unroll
    for (int r = 0; r < 4; ++r) {
      float s = rowsum16(vs[rb][r]);
      float q = rowsum16(vq[rb][r]);
      if ((L & 15) == 15) {
        int row = (2 * w + rb) * 16 + (L >> 4) * 4 + r;
        parts[(size_t)blockIdx.x * 256 + row] = s;
        parts[(size_t)blockIdx.x * 256 + 128 + row] = q;
      }
    }
}

// ============ passB (r18 validated, with M3 carry) ============
__global__ __launch_bounds__(256) void passB_mfma_kernel(
    const unsigned* __restrict__ Y1p,
    const unsigned short* __restrict__ W2b, const unsigned short* __restrict__ W3b,
    const float* __restrict__ A1v, const float* __restrict__ Bc1v,
    const float* __restrict__ A2v, const float* __restrict__ D2v,
    float* __restrict__ parts, unsigned* __restrict__ M3) {
  __shared__ float ab1[128];
  __shared__ __align__(16) unsigned short x1b[64 * 64];
  __shared__ __align__(16) unsigned short x2b[64 * 128];
  const int t = threadIdx.x;
  const int w = t >> 6, L = t & 63;
  if (t < 128) ab1[t] = (t < 64) ? A1v[t] : Bc1v[t - 64];
  bf16x8 w3f[4][4];
#pragma unroll
  for (int rb = 0; rb < 4; ++rb)
#pragma unroll
    for (int ks = 0; ks < 4; ++ks) {
      int row = (4 * w + rb) * 16 + (L & 15);
      int koff = ks * 32 + (L >> 4) * 8;
      w3f[rb][ks] = *reinterpret_cast<const bf16x8*>(&W3b[row * 128 + koff]);
    }
  bf16x8 w2f[2][2];
#pragma unroll
  for (int rb = 0; rb < 2; ++rb)
#pragma unroll
    for (int ks = 0; ks < 2; ++ks) {
      int row = (2 * w + rb) * 16 + (L & 15);
      int koff = ks * 32 + (L >> 4) * 8;
      w2f[rb][ks] = *reinterpret_cast<const bf16x8*>(&W2b[row * 64 + koff]);
    }
  float vs[4][4], vq[4][4];
#pragma unroll
  for (int rb = 0; rb < 4; ++rb)
#pragma unroll
    for (int r = 0; r < 4; ++r) { vs[rb][r] = 0.f; vq[rb][r] = 0.f; }
  char* x1c = reinterpret_cast<char*>(x1b);
  char* x2c = reinterpret_cast<char*>(x2b);
  for (int ch = blockIdx.x; ch < NCH_; ch += 256) {
    const size_t n0 = (size_t)ch * 64;
    __syncthreads();
    stage_x1(Y1p, ab1, x1c, n0, w, L);
    __syncthreads();
#pragma unroll
    for (int rb = 0; rb < 2; ++rb) {
      f32x4 acc2[4];
#pragma unroll
      for (int cb = 0; cb < 4; ++cb) acc2[cb][0] = acc2[cb][1] = acc2[cb][2] = acc2[cb][3] = 0.f;
#pragma unroll
      for (int ks = 0; ks < 2; ++ks)
#pragma unroll
        for (int cb = 0; cb < 4; ++cb) {
          int n = cb * 16 + (L & 15);
          int koff = ks * 32 + (L >> 4) * 8;
          bf16x8 bfr = *reinterpret_cast<const bf16x8*>(&x1c[n * 128 + ((2 * koff) ^ ((n & 7) << 4))]);
          acc2[cb] = __builtin_amdgcn_mfma_f32_16x16x32_bf16(w2f[rb][ks], bfr, acc2[cb], 0, 0, 0);
        }
#pragma unroll
      for (int cb = 0; cb < 4; ++cb) {
        int n = cb * 16 + (L & 15);
        int kbase = (2 * w + rb) * 16 + (L >> 4) * 4;
#pragma unroll
        for (int rp = 0; rp < 2; ++rp) {
          int r0 = 2 * rp;
          float a0 = A2v[kbase + r0], d0 = D2v[kbase + r0];
          float a1 = A2v[kbase + r0 + 1], d1 = D2v[kbase + r0 + 1];
          float v0 = fmaxf(fmaf(acc2[cb][r0], a0, d0), 0.f);
          float v1 = fmaxf(fmaf(acc2[cb][r0 + 1], a1, d1), 0.f);
          unsigned pk = (unsigned)f2bf(v0) | ((unsigned)f2bf(v1) << 16);
          int k0 = kbase + r0;
          *reinterpret_cast<unsigned*>(&x2c[n * 256 + ((2 * k0) ^ ((n & 7) << 4))]) = pk;
        }
      }
    }
    __syncthreads();
    bf16x8 b3[4][4];
#pragma unroll
    for (int cb = 0; cb < 4; ++cb)
#pragma unroll
      for (int ks = 0; ks < 4; ++ks) {
        int n = cb * 16 + (L & 15);
        int koff = ks * 32 + (L >> 4) * 8;
        b3[cb][ks] = *reinterpret_cast<const bf16x8*>(&x2c[n * 256 + ((2 * koff) ^ ((n & 7) << 4))]);
      }
#pragma unroll
    for (int rb = 0; rb < 4; ++rb) {
      f32x4 acc3[4];
#pragma unroll
      for (int cb = 0; cb < 4; ++cb) acc3[cb][0] = acc3[cb][1] = acc3[cb][2] = acc3[cb][3] = 0.f;
#pragma unroll
      for (int ks = 0; ks < 4; ++ks)
#pragma unroll
        for (int cb = 0; cb < 4; ++cb)
          acc3[cb] = __builtin_amdgcn_mfma_f32_16x16x32_bf16(w3f[rb][ks], b3[cb][ks], acc3[cb], 0, 0, 0);
#pragma unroll
      for (int cb = 0; cb < 4; ++cb)
#pragma unroll
        for (int r = 0; r < 4; ++r) {
          float y = acc3[cb][r];
          vs[rb][r] += y;
          vq[rb][r] = fmaf(y, y, vq[rb][r]);
        }
      {
        int rowbase = (4 * w + rb) * 16 + (L >> 4) * 4;
#pragma unroll
        for (int cb = 0; cb < 4; ++cb) {
#pragma unroll
          for (int r = 0; r < 4; ++r) {
            float v = acc3[cb][r];
            int xi = __float_as_int(v), xm = __float_as_int(v);
#define RMAX(CTRL) { int tm_ = __builtin_amdgcn_update_dpp(xi, xi, (CTRL), 0xF, 0xF, false); \
                     xi = __float_as_int(fmaxf(__int_as_float(xi), __int_as_float(tm_))); }
#define RMIN(CTRL) { int tm_ = __builtin_amdgcn_update_dpp(xm, xm, (CTRL), 0xF, 0xF, false); \
                     xm = __float_as_int(fminf(__int_as_float(xm), __int_as_float(tm_))); }
            RMAX(0x111) RMAX(0x112) RMAX(0x114) RMAX(0x118)
            RMIN(0x111) RMIN(0x112) RMIN(0x114) RMIN(0x118)
#undef RMAX
#undef RMIN
            if ((L & 15) == 15) {
              int row = rowbase + r;
              int bs = ch * 4 + cb;
              M3[(size_t)row * NBS_ + bs] =
                  (unsigned)f2bf(__int_as_float(xi)) | ((unsigned)f2bf(__int_as_float(xm)) << 16);
            }
          }
        }
      }
    }
  }
#pragma unroll
  for (int rb = 0; rb < 4; ++rb)
#pragma unroll
    for (int r = 0; r < 4; ++r) {
      float s = rowsum16(vs[rb][r]);
      float q = rowsum16(vq[rb][r]);
      if ((L & 15) == 15) {
        int row = (4 * w + rb) * 16 + (L >> 4) * 4 + r;
        parts[(size_t)blockIdx.x * 512 + row] = s;
        parts[(size_t)blockIdx.x * 512 + 256 + row] = q;
      }
    }
}

// ============ final-small (r18 validated) ============
__global__ __launch_bounds__(256) void final_small_kernel(
    const unsigned* __restrict__ M3, const float* __restrict__ A3,
    const float* __restrict__ D3, float* __restrict__ out1) {
  int gid = blockIdx.x * 256 + threadIdx.x;
  int row = gid / NBS_, bs = gid - row * NBS_;
  unsigned pk = M3[gid];
  float vmax = bfl(pk);
  float vmin = bfh(pk);
  float a = A3[row];
  float v = (a >= 0.f) ? vmax : vmin;
  int b = bs / S_, s = bs - b * S_;
  out1[((size_t)(b * 256 + row)) * S_ + s] = fmaxf(fmaf(v, a, D3[row]), 0.f);
}

extern "C" void kernel_launch(void* const* d_in, const int* in_sizes, int n_in,
                              void* d_out, int out_size, void* d_ws, size_t ws_size,
                              hipStream_t stream) {
  const float* xy  = (const float*)d_in[0];
  const float* fea = (const float*)d_in[1];
  const float* W1  = (const float*)d_in[2];
  const float* b1  = (const float*)d_in[3];
  const float* g1  = (const float*)d_in[4];
  const float* be1 = (const float*)d_in[5];
  const float* W2  = (const float*)d_in[6];
  const float* g2  = (const float*)d_in[8];
  const float* be2 = (const float*)d_in[9];
  const float* W3  = (const float*)d_in[10];
  const float* g3  = (const float*)d_in[12];
  const float* be3 = (const float*)d_in[13];
  float* out = (float*)d_out;
  float* out1 = out + B_ * 2 * S_;

  char* w = (char*)d_ws;
  size_t off = 0;
  auto take = [&](size_t bytes) -> void* {
    void* p = w + off;
    off += (bytes + 255) & ~(size_t)255;
    return p;
  };
  int*      flags   = (int*)take(256);
  int*      fps_idx = (int*)take((size_t)B_ * S_ * 4);
  float*    new_xyz = (float*)take((size_t)B_ * S_ * 2 * 4);
  int*      knn_sel = (int*)take((size_t)NF_ * 4);
  unsigned* Pp      = (unsigned*)take((size_t)B_ * N_ * 32 * 4);
  unsigned* Y1p     = (unsigned*)take((size_t)32 * NF_ * 4);
  float*    parts1  = (float*)take((size_t)256 * 4 * 4);
  float*    A1      = (float*)take(64 * 4);
  float*    Bc1     = (float*)take(64 * 4);
  float*    partsA  = (float*)take((size_t)512 * 256 * 4);
  float*    A2      = (float*)take(128 * 4);
  float*    D2      = (float*)take(128 * 4);
  float*    partsB  = (float*)take((size_t)256 * 512 * 4);
  float*    A3      = (float*)take(256 * 4);
  float*    D3      = (float*)take(256 * 4);
  unsigned short* W2b = (unsigned short*)take((size_t)128 * 64 * 2);
  unsigned short* W3b = (unsigned short*)take((size_t)256 * 128 * 2);
  unsigned* M3      = (unsigned*)take((size_t)256 * NBS_ * 4);

  if (off > ws_size) {
    diag_kernel<<<1, 64, 0, stream>>>(out, (float)(ws_size >> 20));
    return;
  }

  hipMemsetAsync(flags, 0, 256, stream);
  phase0_kernel<<<NBLK, 256, 0, stream>>>(xy, fea, W1, W2, W3, fps_idx, new_xyz,
                                          knn_sel, Pp, W2b, W3b, out, flags);
  yk1_kernel<<<NF_ / 256, 256, 0, stream>>>(xy, knn_sel, new_xyz, Pp, W1, b1, Y1p);

  rowstats_kernel<<<256, 256, 0, stream>>>(Y1p, parts1);
  redabsch1_kernel<<<1, 64, 0, stream>>>(parts1, g1, be1, A1, Bc1);

  passA_mfma_kernel<<<512, 256, 0, stream>>>(Y1p, W2b, A1, Bc1, partsA);
  redabsch_kernel<<<1, 128, 0, stream>>>(partsA, 512, 128, g2, be2, A2, D2);

  passB_mfma_kernel<<<256, 256, 0, stream>>>(Y1p, W2b, W3b, A1, Bc1, A2, D2, partsB, M3);
  redabsch_kernel<<<1, 256, 0, stream>>>(partsB, 256, 256, g3, be3, A3, D3);

  final_small_kernel<<<(256 * NBS_) / 256, 256, 0, stream>>>(M3, A3, D3, out1);
}

// Round 23
// 1224.953 us; speedup vs baseline: 1.0079x; 1.0079x over previous
//
#include <hip/hip_runtime.h>
#include <math.h>

#define B_   16
#define N_   2048
#define S_   1025
#define K_   16
#define EMB_ 64
#define NF_  (B_ * S_ * K_)   // 262400
#define NCH_ (NF_ / 64)       // 4100
#define NBS_ (NCH_ * 4)       // 16400
#define NBLK 256
#define PK_UNITS 513

typedef float v2f __attribute__((ext_vector_type(2)));
typedef short bf16x8 __attribute__((ext_vector_type(8)));
typedef float f32x4 __attribute__((ext_vector_type(4)));

#define AL(p)    __hip_atomic_load((p), __ATOMIC_ACQUIRE, __HIP_MEMORY_SCOPE_AGENT)
#define ASR(p,v) __hip_atomic_store((p), (v), __ATOMIC_RELEASE, __HIP_MEMORY_SCOPE_AGENT)
#define AADD(p)  __hip_atomic_fetch_add((p), 1, __ATOMIC_ACQ_REL, __HIP_MEMORY_SCOPE_AGENT)

__device__ __forceinline__ unsigned short f2bf(float f) {
  unsigned u = __float_as_uint(f);
  u += 0x7fffu + ((u >> 16) & 1u);
  return (unsigned short)(u >> 16);
}
__device__ __forceinline__ float bfl(unsigned pk) { return __uint_as_float((pk & 0xffffu) << 16); }
__device__ __forceinline__ float bfh(unsigned pk) { return __uint_as_float(pk & 0xffff0000u); }

__device__ __forceinline__ float rowsum16(float v) {
#define RADD(CTRL) { int tm_ = __builtin_amdgcn_update_dpp(0, __float_as_int(v), (CTRL), 0xF, 0xF, true); \
                     v += __int_as_float(tm_); }
  RADD(0x111) RADD(0x112) RADD(0x114) RADD(0x118)
#undef RADD
  return v;
}

__global__ void diag_kernel(float* out, float v) {
  if (threadIdx.x == 0 && blockIdx.x == 0) out[0] = v;
}

// ======== phase0: FPS (0-15) || pk (steal) + knn (STATIC b-per-worker) (16-255) ========
// knn: 15 workers per batch, each stages batch coords ONCE then walks s-blocks j=j0+15k
// (2064 -> 240 stagings). progress[b] padded to its own cache line (stride 16 ints).
__global__ __launch_bounds__(256, 1)
void phase0_kernel(const float* __restrict__ xy, const float* __restrict__ fea,
                   const float* __restrict__ W1,
                   const float* __restrict__ W2, const float* __restrict__ W3,
                   int* fps_idx, float* new_xyz, int* knn_sel,
                   unsigned* Pp, unsigned short* W2b, unsigned short* W3b,
                   float* out0, int* flags) {
  __shared__ float2 sh_lxy[N_];     // 16 KB
  __shared__ double sh_lsq[N_];     // 16 KB
  __shared__ float sh_pkA[4096];    // 16 KB
  __shared__ float sh_pkB[4096];    // 16 KB
  __shared__ int sh_unit;
  const int bid = blockIdx.x;
  const int tid = threadIdx.x;
#define PROG(bb) (flags + 16 + 16 * (bb))

  if (bid < 16) {
    // ---- FPS: validated body + padded progress publishing ----
    const int b = bid;
    const int lane = tid;
    const float* xb = xy + (size_t)b * 2 * N_;
    v2f pxp[16], pyp[16];
    float dist[32];
    if (lane < 64) {
      const float2* xb2 = (const float2*)xb;
      const float2* yb2 = (const float2*)(xb + N_);
#pragma unroll
      for (int q = 0; q < 16; ++q) {
        float2 x01 = xb2[lane * 16 + q];
        float2 y01 = yb2[lane * 16 + q];
        int p = lane * 32 + 2 * q;
        sh_lxy[p] = make_float2(x01.x, y01.x);
        sh_lxy[p + 1] = make_float2(x01.y, y01.y);
        pxp[q][0] = x01.x; pxp[q][1] = x01.y;
        pyp[q][0] = y01.x; pyp[q][1] = y01.y;
        dist[2 * q] = __builtin_inff();
        dist[2 * q + 1] = __builtin_inff();
      }
#pragma unroll
      for (int q = 0; q < 16; ++q) {
        asm volatile("" : "+v"(pxp[q]), "+v"(pyp[q]));
      }
    }
    __syncthreads();
    if (lane < 64) {
      int cur = 0;
      for (int t = 0; t < S_; ++t) {
        float2 c = sh_lxy[cur];
        if (lane == 0) {
          fps_idx[b * S_ + t] = cur;
          new_xyz[(b * S_ + t) * 2 + 0] = c.x;
          new_xyz[(b * S_ + t) * 2 + 1] = c.y;
          out0[b * 2 * S_ + t] = c.x;
          out0[b * 2 * S_ + S_ + t] = c.y;
        }
        const float ncx = -c.x, ncy = -c.y;
        v2f ncx2; ncx2[0] = ncx; ncx2[1] = ncx;
        v2f ncy2; ncy2[0] = ncy; ncy2[1] = ncy;
#pragma unroll
        for (int q = 0; q < 16; ++q) {
          v2f dx, dy, sx, sy, dd;
          asm("v_pk_add_f32 %0, %1, %2" : "=v"(dx) : "v"(pxp[q]), "v"(ncx2));
          asm("v_pk_add_f32 %0, %1, %2" : "=v"(dy) : "v"(pyp[q]), "v"(ncy2));
          asm("v_pk_mul_f32 %0, %1, %1" : "=v"(sx) : "v"(dx));
          asm("v_pk_mul_f32 %0, %1, %1" : "=v"(sy) : "v"(dy));
          asm("v_pk_add_f32 %0, %1, %2" : "=v"(dd) : "v"(sx), "v"(sy));
          dist[2 * q] = fminf(dist[2 * q], dd[0]);
          dist[2 * q + 1] = fminf(dist[2 * q + 1], dd[1]);
        }
        float m1[16], m2[8], m3[4], m4[2];
#pragma unroll
        for (int j = 0; j < 16; ++j) m1[j] = fmaxf(dist[2 * j], dist[2 * j + 1]);
#pragma unroll
        for (int j = 0; j < 8; ++j) m2[j] = fmaxf(m1[2 * j], m1[2 * j + 1]);
#pragma unroll
        for (int j = 0; j < 4; ++j) m3[j] = fmaxf(m2[2 * j], m2[2 * j + 1]);
        m4[0] = fmaxf(m3[0], m3[1]);
        m4[1] = fmaxf(m3[2], m3[3]);
        const float lmax = fmaxf(m4[0], m4[1]);
        int xr = __float_as_int(lmax);
#define DPP_MAX_STEP(CTRL)                                                        \
        {                                                                         \
          int tmp_ = __builtin_amdgcn_update_dpp(xr, xr, (CTRL), 0xF, 0xF, false);\
          xr = __float_as_int(fmaxf(__int_as_float(xr), __int_as_float(tmp_)));   \
        }
        DPP_MAX_STEP(0x111)
        DPP_MAX_STEP(0x112)
        DPP_MAX_STEP(0x114)
        DPP_MAX_STEP(0x118)
        DPP_MAX_STEP(0x142)
        DPP_MAX_STEP(0x143)
#undef DPP_MAX_STEP
        const float g = __int_as_float(__builtin_amdgcn_readlane(xr, 63));
        int n = (m4[0] == g) ? 0 : 1;
        float c3 = (n & 1) ? m3[2] : m3[0];
        n = 2 * n + ((c3 == g) ? 0 : 1);
        float lo2 = (n & 1) ? m2[2] : m2[0];
        float hi2 = (n & 1) ? m2[6] : m2[4];
        float c2 = (n & 2) ? hi2 : lo2;
        n = 2 * n + ((c2 == g) ? 0 : 1);
        float a0 = (n & 1) ? m1[2] : m1[0];
        float a1v = (n & 1) ? m1[6] : m1[4];
        float a2v = (n & 1) ? m1[10] : m1[8];
        float a3v = (n & 1) ? m1[14] : m1[12];
        float b0 = (n & 2) ? a1v : a0;
        float b1v = (n & 2) ? a3v : a2v;
        float c1 = (n & 4) ? b1v : b0;
        n = 2 * n + ((c1 == g) ? 0 : 1);
        float e0 = (n & 1) ? dist[2] : dist[0];
        float e1 = (n & 1) ? dist[6] : dist[4];
        float e2 = (n & 1) ? dist[10] : dist[8];
        float e3 = (n & 1) ? dist[14] : dist[12];
        float e4 = (n & 1) ? dist[18] : dist[16];
        float e5 = (n & 1) ? dist[22] : dist[20];
        float e6 = (n & 1) ? dist[26] : dist[24];
        float e7 = (n & 1) ? dist[30] : dist[28];
        float f0 = (n & 2) ? e1 : e0;
        float f1 = (n & 2) ? e3 : e2;
        float f2 = (n & 2) ? e5 : e4;
        float f3 = (n & 2) ? e7 : e6;
        float g0 = (n & 4) ? f1 : f0;
        float g1v = (n & 4) ? f3 : f2;
        float c0 = (n & 8) ? g1v : g0;
        const int lf = 2 * n + ((c0 == g) ? 0 : 1);
        unsigned long long mask = __ballot(lmax == g);
        int first = __ffsll(mask) - 1;
        cur = __builtin_amdgcn_readlane(lane * 32 + lf, first);
        if (lane == 0 && ((t & 31) == 31 || t == S_ - 1)) {
          ASR(PROG(b), t + 1);
        }
      }
    }
  } else {
    // ---- workers: pk / wconv (work-steal) ----
    for (;;) {
      __syncthreads();
      if (tid == 0) sh_unit = AADD(&flags[2]);
      __syncthreads();
      int u = sh_unit;
      if (u >= PK_UNITS) break;
      if (u < 512) {
        const int b = u >> 5;
        const int pt0 = (u & 31) << 6;
#pragma unroll
        for (int p = 0; p < 16; ++p) {
          int idx = tid + 256 * p;
          int c = idx >> 6, e = idx & 63;
          sh_pkA[e * 64 + c] = W1[c * 66 + 2 + e];
          int r = (tid >> 6) + 4 * p, cc = tid & 63;
          sh_pkB[r * 64 + cc] = fea[((size_t)b * 64 + r) * N_ + pt0 + cc];
        }
        __syncthreads();
        const int tpt = tid & 15, tcq = tid >> 4;
        float acc[4][4];
#pragma unroll
        for (int i = 0; i < 4; ++i)
#pragma unroll
          for (int j = 0; j < 4; ++j) acc[i][j] = 0.f;
        for (int e = 0; e < 64; ++e) {
          float4 a4 = *reinterpret_cast<const float4*>(&sh_pkA[e * 64 + tcq * 4]);
          float4 b4 = *reinterpret_cast<const float4*>(&sh_pkB[e * 64 + tpt * 4]);
          const float av[4] = {a4.x, a4.y, a4.z, a4.w};
          const float bvv[4] = {b4.x, b4.y, b4.z, b4.w};
#pragma unroll
          for (int i = 0; i < 4; ++i)
#pragma unroll
            for (int j = 0; j < 4; ++j) acc[i][j] = fmaf(av[i], bvv[j], acc[i][j]);
        }
#pragma unroll
        for (int j = 0; j < 4; ++j) {
          int pt = tpt * 4 + j;
          unsigned lo = (unsigned)f2bf(acc[0][j]) | ((unsigned)f2bf(acc[1][j]) << 16);
          unsigned hi = (unsigned)f2bf(acc[2][j]) | ((unsigned)f2bf(acc[3][j]) << 16);
          unsigned* dst = &Pp[((size_t)(b * N_ + pt0 + pt)) * 32 + tcq * 2];
          dst[0] = lo;
          dst[1] = hi;
        }
      } else {
        for (int i = tid; i < 128 * 64; i += 256) W2b[i] = f2bf(W2[i]);
        for (int i = tid; i < 256 * 128; i += 256) W3b[i] = f2bf(W3[i]);
      }
    }
    // ---- workers: knn, STATIC assignment (15 workers per batch, stage once) ----
    const int wk = bid - 16;          // 0..239
    const int b = wk & 15;            // batch
    const int j0 = wk >> 4;           // 0..14 (s-block phase)
    const float* xb = xy + (size_t)b * 2 * N_;
    __syncthreads();                  // pk LDS reads done before restage
    for (int p = tid; p < N_; p += 256) {
      float x = xb[p], y = xb[N_ + p];
      sh_lxy[p] = make_float2(x, y);
      sh_lsq[p] = (double)x * (double)x + (double)y * (double)y;
    }
    __syncthreads();
    for (int j = j0; j < 129; j += 15) {
      const int s0 = j * 8;
      const int sHi = (s0 + 8 < S_) ? (s0 + 8) : S_;
      if (tid == 0) {
        while (AL(PROG(b)) < sHi) __builtin_amdgcn_s_sleep(8);
      }
      __syncthreads();
      const int s = s0 + (tid >> 5);
      const int oct = tid & 31;
      if (s < S_) {
        const int p0 = AL((int*)&fps_idx[b * S_ + s]);
        float2 q = sh_lxy[p0];
        const double xn = (double)q.x, yn = (double)q.y;
        const double sqn = sh_lsq[p0];
        double d16[16];
        int i16[16];
#pragma unroll
        for (int jj = 0; jj < 16; ++jj) { d16[jj] = __builtin_inf(); i16[jj] = 0x7fffffff; }
        const int mlo = oct * 64;
        for (int m0 = mlo; m0 < mlo + 64; m0 += 4) {
          double dd[4];
#pragma unroll
          for (int u2 = 0; u2 < 4; ++u2) {
            float2 p = sh_lxy[m0 + u2];
            double dot = (double)p.x * xn + (double)p.y * yn;
            dd[u2] = (sqn - 2.0 * dot) + sh_lsq[m0 + u2];
          }
#pragma unroll
          for (int u2 = 0; u2 < 4; ++u2) {
            if (dd[u2] < d16[15]) {
              double d = dd[u2];
              int mi = m0 + u2;
#pragma unroll
              for (int jj = 15; jj >= 1; --jj) {
                bool shift = d < d16[jj - 1];
                bool ins = d < d16[jj];
                d16[jj] = shift ? d16[jj - 1] : (ins ? d : d16[jj]);
                i16[jj] = shift ? i16[jj - 1] : (ins ? mi : i16[jj]);
              }
              if (d < d16[0]) { d16[0] = d; i16[0] = mi; }
            }
          }
        }
#pragma unroll
        for (int w = 1; w <= 16; w <<= 1) {
          double nd[16]; int ni[16];
#pragma unroll
          for (int i = 0; i < 16; ++i) {
            double rd = __shfl_xor(d16[15 - i], w, 64);
            int ri = __shfl_xor(i16[15 - i], w, 64);
            bool takeR = (rd < d16[i]) || (rd == d16[i] && ri < i16[i]);
            nd[i] = takeR ? rd : d16[i];
            ni[i] = takeR ? ri : i16[i];
          }
#pragma unroll
          for (int i = 0; i < 16; ++i) { d16[i] = nd[i]; i16[i] = ni[i]; }
          if (w < 16) {
#pragma unroll
            for (int dstg = 8; dstg >= 1; dstg >>= 1) {
#pragma unroll
              for (int i = 0; i < 16; ++i) {
                if ((i & dstg) == 0) {
                  int a = i, c = i + dstg;
                  bool sw = (d16[a] > d16[c]) || (d16[a] == d16[c] && i16[a] > i16[c]);
                  double tlo = sw ? d16[c] : d16[a];
                  double thi = sw ? d16[a] : d16[c];
                  int ulo = sw ? i16[c] : i16[a];
                  int uhi = sw ? i16[a] : i16[c];
                  d16[a] = tlo; d16[c] = thi; i16[a] = ulo; i16[c] = uhi;
                }
              }
            }
          }
        }
        if (oct == 0) {
          int* dst = knn_sel + ((size_t)b * S_ + s) * K_;
#pragma unroll
          for (int jj = 0; jj < 16; ++jj) dst[jj] = i16[jj];
        }
      }
    }
  }
#undef PROG
}

// ---------------- yk1 (r18 validated) ----------------
__global__ __launch_bounds__(256) void yk1_kernel(const float* __restrict__ xy,
                                                  const int* __restrict__ knn_sel,
                                                  const float* __restrict__ new_xyz,
                                                  const unsigned* __restrict__ Pp,
                                                  const float* __restrict__ W1,
                                                  const float* __restrict__ b1,
                                                  unsigned* __restrict__ Y1p) {
  __shared__ float w0s[64], w1s[64], bbs[64];
  const int t = threadIdx.x;
  if (t < 64) { w0s[t] = W1[t * 66 + 0]; w1s[t] = W1[t * 66 + 1]; bbs[t] = b1[t]; }
  __syncthreads();
  const int n = blockIdx.x * 256 + t;
  const int bs = n >> 4;
  const int b = bs / S_;
  const int nbr = knn_sel[n];
  const float dx = xy[(size_t)b * 2 * N_ + nbr] - new_xyz[bs * 2 + 0];
  const float dy = xy[(size_t)b * 2 * N_ + N_ + nbr] - new_xyz[bs * 2 + 1];
  const unsigned* prow = &Pp[((size_t)(b * N_ + nbr)) * 32];
#pragma unroll 8
  for (int j = 0; j < 32; ++j) {
    unsigned pj = prow[j];
    int c = 2 * j;
    float v0 = bfl(pj) + w0s[c] * dx + w1s[c] * dy + bbs[c];
    float v1 = bfh(pj) + w0s[c + 1] * dx + w1s[c + 1] * dy + bbs[c + 1];
    Y1p[(size_t)j * NF_ + n] = (unsigned)f2bf(v0) | ((unsigned)f2bf(v1) << 16);
  }
}

// ---------------- rowstats (r18 validated) ----------------
__global__ __launch_bounds__(256) void rowstats_kernel(const unsigned* __restrict__ Y1p,
                                                       float* __restrict__ parts) {
  const int j = blockIdx.x & 31;
  const int seg = blockIdx.x >> 5;
  const int SEG = NF_ / 8;
  const unsigned* p = Y1p + (size_t)j * NF_ + (size_t)seg * SEG;
  double s0 = 0, q0 = 0, s1 = 0, q1 = 0;
  for (int i = threadIdx.x; i < SEG; i += 256) {
    unsigned pk = p[i];
    double a = (double)bfl(pk), b = (double)bfh(pk);
    s0 += a; q0 = fma(a, a, q0);
    s1 += b; q1 = fma(b, b, q1);
  }
  __shared__ double sh[4][256];
  sh[0][threadIdx.x] = s0; sh[1][threadIdx.x] = q0;
  sh[2][threadIdx.x] = s1; sh[3][threadIdx.x] = q1;
  __syncthreads();
  for (int o = 128; o > 0; o >>= 1) {
    if (threadIdx.x < o) {
#pragma unroll
      for (int u = 0; u < 4; ++u) sh[u][threadIdx.x] += sh[u][threadIdx.x + o];
    }
    __syncthreads();
  }
  if (threadIdx.x == 0) {
    float* dst = parts + (size_t)(j * 8 + seg) * 4;
    dst[0] = (float)sh[0][0];
    dst[1] = (float)sh[2][0];
    dst[2] = (float)sh[1][0];
    dst[3] = (float)sh[3][0];
  }
}

// ---------------- redabsch1 (r18 validated) ----------------
__global__ void redabsch1_kernel(const float* __restrict__ parts,
                                 const float* __restrict__ g, const float* __restrict__ be,
                                 float* __restrict__ A, float* __restrict__ D) {
  int m = threadIdx.x;
  if (m >= 64) return;
  int j = m >> 1, par = m & 1;
  double a = 0.0, b = 0.0;
  for (int seg = 0; seg < 8; ++seg) {
    const float* src = parts + (size_t)(j * 8 + seg) * 4;
    a += (double)src[par];
    b += (double)src[2 + par];
  }
  double mu = a * (1.0 / NF_);
  double var = b * (1.0 / NF_) - mu * mu;
  double aa = (double)g[m] / sqrt(var + 1e-5);
  A[m] = (float)aa;
  D[m] = (float)((double)be[m] - aa * mu);
}

// ---------------- redabsch (r18 validated) ----------------
__global__ void redabsch_kernel(const float* __restrict__ parts, int P, int M,
                                const float* __restrict__ g, const float* __restrict__ be,
                                float* __restrict__ A, float* __restrict__ D) {
  int m = threadIdx.x;
  if (m >= M) return;
  double a = 0.0, b = 0.0;
  for (int p = 0; p < P; ++p) {
    a += (double)parts[(size_t)p * 2 * M + m];
    b += (double)parts[(size_t)p * 2 * M + M + m];
  }
  double mu = a * (1.0 / NF_);
  double var = b * (1.0 / NF_) - mu * mu;
  double aa = (double)g[m] / sqrt(var + 1e-5);
  A[m] = (float)aa;
  D[m] = (float)((double)be[m] - aa * mu);
}

__device__ __forceinline__ void stage_x1(const unsigned* Y1p, const float* ab1, char* x1c,
                                         size_t n0, int w, int L) {
#pragma unroll
  for (int e = 0; e < 8; ++e) {
    int k0 = 2 * (w + 4 * e);
    unsigned pkv = Y1p[(size_t)(k0 >> 1) * NF_ + n0 + L];
    float v0 = fmaxf(fmaf(bfl(pkv), ab1[k0], ab1[64 + k0]), 0.f);
    float v1 = fmaxf(fmaf(bfh(pkv), ab1[k0 + 1], ab1[64 + k0 + 1]), 0.f);
    unsigned pk = (unsigned)f2bf(v0) | ((unsigned)f2bf(v1) << 16);
    *reinterpret_cast<unsigned*>(&x1c[L * 128 + ((2 * k0) ^ ((L & 7) << 4))]) = pk;
  }
}

// ============ passA (r18 validated) ============
__global__ __launch_bounds__(256) void passA_mfma_kernel(
    const unsigned* __restrict__ Y1p, const unsigned short* __restrict__ W2b,
    const float* __restrict__ A1v, const float* __restrict__ Bc1v,
    float* __restrict__ parts) {
  __shared__ float ab1[128];
  __shared__ __align__(16) unsigned short x1b[64 * 64];
  const int t = threadIdx.x;
  const int w = t >> 6, L = t & 63;
  if (t < 128) ab1[t] = (t < 64) ? A1v[t] : Bc1v[t - 64];
  bf16x8 w2f[2][2];
#pragma unroll
  for (int rb = 0; rb < 2; ++rb)
#pragma unroll
    for (int ks = 0; ks < 2; ++ks) {
      int row = (2 * w + rb) * 16 + (L & 15);
      int koff = ks * 32 + (L >> 4) * 8;
      w2f[rb][ks] = *reinterpret_cast<const bf16x8*>(&W2b[row * 64 + koff]);
    }
  float vs[2][4], vq[2][4];
#pragma unroll
  for (int rb = 0; rb < 2; ++rb)
#pragma unroll
    for (int r = 0; r < 4; ++r) { vs[rb][r] = 0.f; vq[rb][r] = 0.f; }
  char* x1c = reinterpret_cast<char*>(x1b);
  for (int ch = blockIdx.x; ch < NCH_; ch += 512) {
    const size_t n0 = (size_t)ch * 64;
    __syncthreads();
    stage_x1(Y1p, ab1, x1c, n0, w, L);
    __syncthreads();
#pragma unroll
    for (int rb = 0; rb < 2; ++rb) {
      f32x4 acc2[4];
#pragma unroll
      for (int cb = 0; cb < 4; ++cb) acc2[cb][0] = acc2[cb][1] = acc2[cb][2] = acc2[cb][3] = 0.f;
#pragma unroll
      for (int ks = 0; ks < 2; ++ks)
#pragma unroll
        for (int cb = 0; cb < 4; ++cb) {
          int n = cb * 16 + (L & 15);
          int koff = ks * 32 + (L >> 4) * 8;
          bf16x8 bfr = *reinterpret_cast<const bf16x8*>(&x1c[n * 128 + ((2 * koff) ^ ((n & 7) << 4))]);
          acc2[cb] = __builtin_amdgcn_mfma_f32_16x16x32_bf16(w2f[rb][ks], bfr, acc2[cb], 0, 0, 0);
        }
#pragma unroll
      for (int cb = 0; cb < 4; ++cb)
#pragma unroll
        for (int r = 0; r < 4; ++r) {
          float y = acc2[cb][r];
          vs[rb][r] += y;
          vq[rb][r] = fmaf(y, y, vq[rb][r]);
        }
    }
  }
#pragma unroll
  for (int rb = 0; rb < 2; ++rb)
#pragma unroll
    for (int r = 0; r < 4; ++r) {
      float s = rowsum16(vs[rb][r]);
      float q = rowsum16(vq[rb][r]);
      if ((L & 15) == 15) {
        int row = (2 * w + rb) * 16 + (L >> 4) * 4 + r;
        parts[(size_t)blockIdx.x * 256 + row] = s;
        parts[(size_t)blockIdx.x * 256 + 128 + row] = q;
      }
    }
}

// ============ passB (r18 validated, with M3 carry) ============
__global__ __launch_bounds__(256) void passB_mfma_kernel(
    const unsigned* __restrict__ Y1p,
    const unsigned short* __restrict__ W2b, const unsigned short* __restrict__ W3b,
    const float* __restrict__ A1v, const float* __restrict__ Bc1v,
    const float* __restrict__ A2v, const float* __restrict__ D2v,
    float* __restrict__ parts, unsigned* __restrict__ M3) {
  __shared__ float ab1[128];
  __shared__ __align__(16) unsigned short x1b[64 * 64];
  __shared__ __align__(16) unsigned short x2b[64 * 128];
  const int t = threadIdx.x;
  const int w = t >> 6, L = t & 63;
  if (t < 128) ab1[t] = (t < 64) ? A1v[t] : Bc1v[t - 64];
  bf16x8 w3f[4][4];
#pragma unroll
  for (int rb = 0; rb < 4; ++rb)
#pragma unroll
    for (int ks = 0; ks < 4; ++ks) {
      int row = (4 * w + rb) * 16 + (L & 15);
      int koff = ks * 32 + (L >> 4) * 8;
      w3f[rb][ks] = *reinterpret_cast<const bf16x8*>(&W3b[row * 128 + koff]);
    }
  bf16x8 w2f[2][2];
#pragma unroll
  for (int rb = 0; rb < 2; ++rb)
#pragma unroll
    for (int ks = 0; ks < 2; ++ks) {
      int row = (2 * w + rb) * 16 + (L & 15);
      int koff = ks * 32 + (L >> 4) * 8;
      w2f[rb][ks] = *reinterpret_cast<const bf16x8*>(&W2b[row * 64 + koff]);
    }
  float vs[4][4], vq[4][4];
#pragma unroll
  for (int rb = 0; rb < 4; ++rb)
#pragma unroll
    for (int r = 0; r < 4; ++r) { vs[rb][r] = 0.f; vq[rb][r] = 0.f; }
  char* x1c = reinterpret_cast<char*>(x1b);
  char* x2c = reinterpret_cast<char*>(x2b);
  for (int ch = blockIdx.x; ch < NCH_; ch += 256) {
    const size_t n0 = (size_t)ch * 64;
    __syncthreads();
    stage_x1(Y1p, ab1, x1c, n0, w, L);
    __syncthreads();
#pragma unroll
    for (int rb = 0; rb < 2; ++rb) {
      f32x4 acc2[4];
#pragma unroll
      for (int cb = 0; cb < 4; ++cb) acc2[cb][0] = acc2[cb][1] = acc2[cb][2] = acc2[cb][3] = 0.f;
#pragma unroll
      for (int ks = 0; ks < 2; ++ks)
#pragma unroll
        for (int cb = 0; cb < 4; ++cb) {
          int n = cb * 16 + (L & 15);
          int koff = ks * 32 + (L >> 4) * 8;
          bf16x8 bfr = *reinterpret_cast<const bf16x8*>(&x1c[n * 128 + ((2 * koff) ^ ((n & 7) << 4))]);
          acc2[cb] = __builtin_amdgcn_mfma_f32_16x16x32_bf16(w2f[rb][ks], bfr, acc2[cb], 0, 0, 0);
        }
#pragma unroll
      for (int cb = 0; cb < 4; ++cb) {
        int n = cb * 16 + (L & 15);
        int kbase = (2 * w + rb) * 16 + (L >> 4) * 4;
#pragma unroll
        for (int rp = 0; rp < 2; ++rp) {
          int r0 = 2 * rp;
          float a0 = A2v[kbase + r0], d0 = D2v[kbase + r0];
          float a1 = A2v[kbase + r0 + 1], d1 = D2v[kbase + r0 + 1];
          float v0 = fmaxf(fmaf(acc2[cb][r0], a0, d0), 0.f);
          float v1 = fmaxf(fmaf(acc2[cb][r0 + 1], a1, d1), 0.f);
          unsigned pk = (unsigned)f2bf(v0) | ((unsigned)f2bf(v1) << 16);
          int k0 = kbase + r0;
          *reinterpret_cast<unsigned*>(&x2c[n * 256 + ((2 * k0) ^ ((n & 7) << 4))]) = pk;
        }
      }
    }
    __syncthreads();
    bf16x8 b3[4][4];
#pragma unroll
    for (int cb = 0; cb < 4; ++cb)
#pragma unroll
      for (int ks = 0; ks < 4; ++ks) {
        int n = cb * 16 + (L & 15);
        int koff = ks * 32 + (L >> 4) * 8;
        b3[cb][ks] = *reinterpret_cast<const bf16x8*>(&x2c[n * 256 + ((2 * koff) ^ ((n & 7) << 4))]);
      }
#pragma unroll
    for (int rb = 0; rb < 4; ++rb) {
      f32x4 acc3[4];
#pragma unroll
      for (int cb = 0; cb < 4; ++cb) acc3[cb][0] = acc3[cb][1] = acc3[cb][2] = acc3[cb][3] = 0.f;
#pragma unroll
      for (int ks = 0; ks < 4; ++ks)
#pragma unroll
        for (int cb = 0; cb < 4; ++cb)
          acc3[cb] = __builtin_amdgcn_mfma_f32_16x16x32_bf16(w3f[rb][ks], b3[cb][ks], acc3[cb], 0, 0, 0);
#pragma unroll
      for (int cb = 0; cb < 4; ++cb)
#pragma unroll
        for (int r = 0; r < 4; ++r) {
          float y = acc3[cb][r];
          vs[rb][r] += y;
          vq[rb][r] = fmaf(y, y, vq[rb][r]);
        }
      {
        int rowbase = (4 * w + rb) * 16 + (L >> 4) * 4;
#pragma unroll
        for (int cb = 0; cb < 4; ++cb) {
#pragma unroll
          for (int r = 0; r < 4; ++r) {
            float v = acc3[cb][r];
            int xi = __float_as_int(v), xm = __float_as_int(v);
#define RMAX(CTRL) { int tm_ = __builtin_amdgcn_update_dpp(xi, xi, (CTRL), 0xF, 0xF, false); \
                     xi = __float_as_int(fmaxf(__int_as_float(xi), __int_as_float(tm_))); }
#define RMIN(CTRL) { int tm_ = __builtin_amdgcn_update_dpp(xm, xm, (CTRL), 0xF, 0xF, false); \
                     xm = __float_as_int(fminf(__int_as_float(xm), __int_as_float(tm_))); }
            RMAX(0x111) RMAX(0x112) RMAX(0x114) RMAX(0x118)
            RMIN(0x111) RMIN(0x112) RMIN(0x114) RMIN(0x118)
#undef RMAX
#undef RMIN
            if ((L & 15) == 15) {
              int row = rowbase + r;
              int bs = ch * 4 + cb;
              M3[(size_t)row * NBS_ + bs] =
                  (unsigned)f2bf(__int_as_float(xi)) | ((unsigned)f2bf(__int_as_float(xm)) << 16);
            }
          }
        }
      }
    }
  }
#pragma unroll
  for (int rb = 0; rb < 4; ++rb)
#pragma unroll
    for (int r = 0; r < 4; ++r) {
      float s = rowsum16(vs[rb][r]);
      float q = rowsum16(vq[rb][r]);
      if ((L & 15) == 15) {
        int row = (4 * w + rb) * 16 + (L >> 4) * 4 + r;
        parts[(size_t)blockIdx.x * 512 + row] = s;
        parts[(size_t)blockIdx.x * 512 + 256 + row] = q;
      }
    }
}

// ============ final-small (r18 validated) ============
__global__ __launch_bounds__(256) void final_small_kernel(
    const unsigned* __restrict__ M3, const float* __restrict__ A3,
    const float* __restrict__ D3, float* __restrict__ out1) {
  int gid = blockIdx.x * 256 + threadIdx.x;
  int row = gid / NBS_, bs = gid - row * NBS_;
  unsigned pk = M3[gid];
  float vmax = bfl(pk);
  float vmin = bfh(pk);
  float a = A3[row];
  float v = (a >= 0.f) ? vmax : vmin;
  int b = bs / S_, s = bs - b * S_;
  out1[((size_t)(b * 256 + row)) * S_ + s] = fmaxf(fmaf(v, a, D3[row]), 0.f);
}

extern "C" void kernel_launch(void* const* d_in, const int* in_sizes, int n_in,
                              void* d_out, int out_size, void* d_ws, size_t ws_size,
                              hipStream_t stream) {
  const float* xy  = (const float*)d_in[0];
  const float* fea = (const float*)d_in[1];
  const float* W1  = (const float*)d_in[2];
  const float* b1  = (const float*)d_in[3];
  const float* g1  = (const float*)d_in[4];
  const float* be1 = (const float*)d_in[5];
  const float* W2  = (const float*)d_in[6];
  const float* g2  = (const float*)d_in[8];
  const float* be2 = (const float*)d_in[9];
  const float* W3  = (const float*)d_in[10];
  const float* g3  = (const float*)d_in[12];
  const float* be3 = (const float*)d_in[13];
  float* out = (float*)d_out;
  float* out1 = out + B_ * 2 * S_;

  char* w = (char*)d_ws;
  size_t off = 0;
  auto take = [&](size_t bytes) -> void* {
    void* p = w + off;
    off += (bytes + 255) & ~(size_t)255;
    return p;
  };
  int*      flags   = (int*)take(2048);   // [2]=pk ctr; progress[b] at [16+16b] (64B lines)
  int*      fps_idx = (int*)take((size_t)B_ * S_ * 4);
  float*    new_xyz = (float*)take((size_t)B_ * S_ * 2 * 4);
  int*      knn_sel = (int*)take((size_t)NF_ * 4);
  unsigned* Pp      = (unsigned*)take((size_t)B_ * N_ * 32 * 4);
  unsigned* Y1p     = (unsigned*)take((size_t)32 * NF_ * 4);
  float*    parts1  = (float*)take((size_t)256 * 4 * 4);
  float*    A1      = (float*)take(64 * 4);
  float*    Bc1     = (float*)take(64 * 4);
  float*    partsA  = (float*)take((size_t)512 * 256 * 4);
  float*    A2      = (float*)take(128 * 4);
  float*    D2      = (float*)take(128 * 4);
  float*    partsB  = (float*)take((size_t)256 * 512 * 4);
  float*    A3      = (float*)take(256 * 4);
  float*    D3      = (float*)take(256 * 4);
  unsigned short* W2b = (unsigned short*)take((size_t)128 * 64 * 2);
  unsigned short* W3b = (unsigned short*)take((size_t)256 * 128 * 2);
  unsigned* M3      = (unsigned*)take((size_t)256 * NBS_ * 4);

  if (off > ws_size) {
    diag_kernel<<<1, 64, 0, stream>>>(out, (float)(ws_size >> 20));
    return;
  }

  hipMemsetAsync(flags, 0, 2048, stream);
  phase0_kernel<<<NBLK, 256, 0, stream>>>(xy, fea, W1, W2, W3, fps_idx, new_xyz,
                                          knn_sel, Pp, W2b, W3b, out, flags);
  yk1_kernel<<<NF_ / 256, 256, 0, stream>>>(xy, knn_sel, new_xyz, Pp, W1, b1, Y1p);

  rowstats_kernel<<<256, 256, 0, stream>>>(Y1p, parts1);
  redabsch1_kernel<<<1, 64, 0, stream>>>(parts1, g1, be1, A1, Bc1);

  passA_mfma_kernel<<<512, 256, 0, stream>>>(Y1p, W2b, A1, Bc1, partsA);
  redabsch_kernel<<<1, 128, 0, stream>>>(partsA, 512, 128, g2, be2, A2, D2);

  passB_mfma_kernel<<<256, 256, 0, stream>>>(Y1p, W2b, W3b, A1, Bc1, A2, D2, partsB, M3);
  redabsch_kernel<<<1, 256, 0, stream>>>(partsB, 256, 256, g3, be3, A3, D3);

  final_small_kernel<<<(256 * NBS_) / 256, 256, 0, stream>>>(M3, A3, D3, out1);
}